// Round 2
// baseline (320.918 us; speedup 1.0000x reference)
//
#include <hip/hip_runtime.h>
#include <math.h>

#define NN   8192
#define NB   4
#define NE   262144
#define EMB  64
#define HID  512
#define NOUT 64
#define TILE 32
#define NTHREADS 512

// ---------------- Kernel 1: edge counting ----------------
// deg[b*NN+u]   = #edges (u, *) in graph b  (with multiplicity)
// cnt[(b*NN+u)*4 + j] = #edges (u, perturb[j]) in graph b
__global__ __launch_bounds__(256) void count_kernel(const int* __restrict__ ei,
                                                    const int* __restrict__ pert,
                                                    int* __restrict__ deg,
                                                    int* __restrict__ cnt) {
    int p0 = pert[0], p1 = pert[1], p2 = pert[2], p3 = pert[3];
    int g = blockIdx.x * 256 + threadIdx.x;          // 0 .. NB*NE-1 (exact grid)
    int b = g >> 18;                                  // NE = 2^18
    int e = g & (NE - 1);
    const int* base = ei + (size_t)b * 2 * NE;
    int src = base[e];
    int dst = base[NE + e];
    int row = b * NN + src;
    atomicAdd(&deg[row], 1);
    if (dst == p0) atomicAdd(&cnt[row * 4 + 0], 1);
    if (dst == p1) atomicAdd(&cnt[row * 4 + 1], 1);
    if (dst == p2) atomicAdd(&cnt[row * 4 + 2], 1);
    if (dst == p3) atomicAdd(&cnt[row * 4 + 3], 1);
}

// ---------------- Kernel 2: fold the 4 hops of w1 ----------------
// omega = stack([H]*4, axis=-1).reshape(N, 256) => omega[n, e*4+hop] = H[n, e]
// so w1_eff[h*64+e] = sum_{q=0..3} w1[h*256 + e*4 + q]   (hop is FASTEST axis)
__global__ __launch_bounds__(256) void prep_kernel(const float* __restrict__ w1,
                                                   float* __restrict__ w1_eff) {
    int i = blockIdx.x * 256 + threadIdx.x;          // 0 .. 32767 (exact grid)
    float4 r = *(const float4*)(w1 + (size_t)i * 4);
    w1_eff[i] = r.x + r.y + r.z + r.w;
}

// ---------------- Kernel 3: fused node pipeline ----------------
__global__ __launch_bounds__(512) void node_kernel(
    const int* __restrict__ deg, const int* __restrict__ cnt,
    const float* __restrict__ proj_w, const float* __restrict__ proj_b,
    const float* __restrict__ w1_eff, const float* __restrict__ b1,
    const float* __restrict__ ln_g, const float* __restrict__ ln_b,
    const float* __restrict__ w2, const float* __restrict__ b2,
    float* __restrict__ out)
{
    __shared__ float Hs[TILE * EMB];        // 8 KB, XOR-swizzled 16B chunks
    __shared__ float G[TILE][HID];          // 64 KB
    __shared__ float wred[8][TILE][2];      // per-wave (sum, sumsq) partials, 2 KB

    int tid = threadIdx.x;
    int node0 = blockIdx.x * TILE;          // global node id = b*NN + n, flat over B*NN

    // ---- Phase 1: H tile ----
    // H[n][e] = deg * proj_b[e] + sum_j cnt[j] * proj_w[e*4+j]
    for (int i = tid; i < TILE * EMB; i += NTHREADS) {
        int n = i >> 6, e = i & 63;
        int gn = node0 + n;
        float d = (float)deg[gn];
        int4 c = *(const int4*)(cnt + gn * 4);
        const float* pw = proj_w + e * 4;
        float h = d * proj_b[e]
                + (float)c.x * pw[0] + (float)c.y * pw[1]
                + (float)c.z * pw[2] + (float)c.w * pw[3];
        int chunk = (e >> 2) ^ ((n >> 3) & 3);             // swizzle vs 256B row stride
        Hs[n * EMB + chunk * 4 + (e & 3)] = h;
    }
    __syncthreads();

    // ---- Phase 2: h_pre = w1_eff @ H + b1  (thread tile: 8 nodes x 4 h) ----
    int ng = tid & 3;          // node group -> nodes ng*8 .. ng*8+7
    int hg = tid >> 2;         // 0..127     -> h = hg*4 .. hg*4+3
    int n0 = ng * 8;
    int h0 = hg * 4;

    float acc[8][4];
    #pragma unroll
    for (int i = 0; i < 8; ++i)
        #pragma unroll
        for (int j = 0; j < 4; ++j) acc[i][j] = 0.f;

    #pragma unroll 4
    for (int ec = 0; ec < 16; ++ec) {
        float4 wv[4];
        #pragma unroll
        for (int j = 0; j < 4; ++j)
            wv[j] = *(const float4*)(w1_eff + (h0 + j) * EMB + ec * 4);
        int chunk = ec ^ ng;                               // (n>>3)&3 == ng for this thread
        #pragma unroll
        for (int i = 0; i < 8; ++i) {
            float4 hv = *(const float4*)(Hs + (n0 + i) * EMB + chunk * 4);
            #pragma unroll
            for (int j = 0; j < 4; ++j)
                acc[i][j] += hv.x * wv[j].x + hv.y * wv[j].y
                           + hv.z * wv[j].z + hv.w * wv[j].w;
        }
    }
    float4 bv = *(const float4*)(b1 + h0);
    #pragma unroll
    for (int i = 0; i < 8; ++i) {
        acc[i][0] += bv.x; acc[i][1] += bv.y; acc[i][2] += bv.z; acc[i][3] += bv.w;
    }

    // ---- Phase 3: LayerNorm stats (wave shfl reduce over h-groups, then LDS) ----
    int lane = tid & 63;
    int wid  = tid >> 6;
    #pragma unroll
    for (int i = 0; i < 8; ++i) {
        float s  = acc[i][0] + acc[i][1] + acc[i][2] + acc[i][3];
        float ss = acc[i][0]*acc[i][0] + acc[i][1]*acc[i][1]
                 + acc[i][2]*acc[i][2] + acc[i][3]*acc[i][3];
        #pragma unroll
        for (int d = 4; d < 64; d <<= 1) {
            s  += __shfl_xor(s,  d, 64);
            ss += __shfl_xor(ss, d, 64);
        }
        if (lane < 4) {                    // lane == ng holds this ng's partial
            wred[wid][n0 + i][0] = s;
            wred[wid][n0 + i][1] = ss;
        }
    }
    __syncthreads();

    float mu[8], rs[8];
    #pragma unroll
    for (int i = 0; i < 8; ++i) {
        float s = 0.f, ss = 0.f;
        #pragma unroll
        for (int w = 0; w < 8; ++w) { s += wred[w][n0 + i][0]; ss += wred[w][n0 + i][1]; }
        float m = s * (1.0f / 512.0f);
        float var = ss * (1.0f / 512.0f) - m * m;
        mu[i] = m;
        rs[i] = rsqrtf(var + 1e-5f);
    }

    // ---- Phase 3b: LN affine + exact GELU -> G tile ----
    float4 lgv = *(const float4*)(ln_g + h0);
    float4 lbv = *(const float4*)(ln_b + h0);
    const float lg[4] = {lgv.x, lgv.y, lgv.z, lgv.w};
    const float lb[4] = {lbv.x, lbv.y, lbv.z, lbv.w};
    #pragma unroll
    for (int i = 0; i < 8; ++i) {
        float4 gv;
        float* gp = &gv.x;
        #pragma unroll
        for (int j = 0; j < 4; ++j) {
            float x = (acc[i][j] - mu[i]) * rs[i] * lg[j] + lb[j];
            gp[j] = 0.5f * x * (1.0f + erff(x * 0.70710678118654752f));
        }
        *(float4*)(&G[n0 + i][h0]) = gv;
    }
    __syncthreads();

    // ---- Phase 4: out = G @ w2^T + b2  (thread: 4 nodes x 1 output col) ----
    int o    = tid & 63;
    int ng2  = tid >> 6;       // == wave id -> G reads are wave-uniform (broadcast)
    int na   = ng2 * 4;
    float oacc[4] = {0.f, 0.f, 0.f, 0.f};
    const float4* w2r = (const float4*)(w2 + o * HID);
    #pragma unroll 8
    for (int hc = 0; hc < HID / 4; ++hc) {
        float4 w4 = w2r[hc];
        #pragma unroll
        for (int i = 0; i < 4; ++i) {
            float4 gv = *(const float4*)(&G[na + i][hc * 4]);
            oacc[i] += gv.x * w4.x + gv.y * w4.y + gv.z * w4.z + gv.w * w4.w;
        }
    }
    float bo = b2[o];
    #pragma unroll
    for (int i = 0; i < 4; ++i)
        out[(size_t)(node0 + na + i) * NOUT + o] = oacc[i] + bo;
}

// ---------------- launch ----------------
extern "C" void kernel_launch(void* const* d_in, const int* in_sizes, int n_in,
                              void* d_out, int out_size, void* d_ws, size_t ws_size,
                              hipStream_t stream) {
    const int*   ei     = (const int*)d_in[0];
    const int*   pert   = (const int*)d_in[1];
    const float* proj_w = (const float*)d_in[2];
    const float* proj_b = (const float*)d_in[3];
    const float* w1     = (const float*)d_in[4];
    const float* b1     = (const float*)d_in[5];
    const float* ln_g   = (const float*)d_in[6];
    const float* ln_b   = (const float*)d_in[7];
    const float* w2     = (const float*)d_in[8];
    const float* b2     = (const float*)d_in[9];
    float* out = (float*)d_out;

    char* ws = (char*)d_ws;
    int*   deg    = (int*)ws;                                  // 32768 ints
    int*   cnt    = (int*)(ws + 32768 * 4);                    // 131072 ints
    float* w1_eff = (float*)(ws + 32768 * 4 + 131072 * 4);     // 32768 floats

    hipMemsetAsync(ws, 0, (32768 + 131072) * 4, stream);

    count_kernel<<<(NB * NE) / 256, 256, 0, stream>>>(ei, pert, deg, cnt);
    prep_kernel<<<(HID * EMB) / 256, 256, 0, stream>>>(w1, w1_eff);
    node_kernel<<<(NB * NN) / TILE, NTHREADS, 0, stream>>>(
        deg, cnt, proj_w, proj_b, w1_eff, b1, ln_g, ln_b, w2, b2, out);
}

// Round 4
// 199.425 us; speedup vs baseline: 1.6092x; 1.6092x over previous
//
#include <hip/hip_runtime.h>
#include <math.h>

#define NN   8192
#define NB   4
#define NE   262144
#define EMB  64
#define HID  512
#define NOUT 64
#define DMAX 256          // table covers deg in [0, DMAX); deg>=DMAX -> special path

// ---------------- Kernel 1: edge counting ----------------
// deg[b*NN+u]   = #edges (u, *) in graph b  (with multiplicity)
// cnt[(b*NN+u)*4 + j] = #edges (u, perturb[j]) in graph b
__global__ __launch_bounds__(256) void count_kernel(const int* __restrict__ ei,
                                                    const int* __restrict__ pert,
                                                    int* __restrict__ deg,
                                                    int* __restrict__ cnt) {
    int p0 = pert[0], p1 = pert[1], p2 = pert[2], p3 = pert[3];
    int g = blockIdx.x * 256 + threadIdx.x;          // 0 .. NB*NE-1 (exact grid)
    int b = g >> 18;                                  // NE = 2^18
    int e = g & (NE - 1);
    const int* base = ei + (size_t)b * 2 * NE;
    int src = base[e];
    int dst = base[NE + e];
    int row = b * NN + src;
    atomicAdd(&deg[row], 1);
    if (dst == p0) atomicAdd(&cnt[row * 4 + 0], 1);
    if (dst == p1) atomicAdd(&cnt[row * 4 + 1], 1);
    if (dst == p2) atomicAdd(&cnt[row * 4 + 2], 1);
    if (dst == p3) atomicAdd(&cnt[row * 4 + 3], 1);
}

// ---------------- Kernel 1b: compact list of special nodes ----------------
__global__ __launch_bounds__(256) void classify_kernel(const int* __restrict__ deg,
                                                       const int* __restrict__ cnt,
                                                       int* __restrict__ nspec,
                                                       int* __restrict__ spec) {
    int gn = blockIdx.x * 256 + threadIdx.x;         // 0 .. NB*NN-1 (exact grid)
    int4 c = *(const int4*)(cnt + gn * 4);
    bool sp = ((c.x | c.y | c.z | c.w) != 0) || (deg[gn] >= DMAX);
    if (sp) {
        int i = atomicAdd(nspec, 1);
        spec[i] = gn;
    }
}

// ---------------- Kernel 2: fold the 4 hops of w1 ----------------
// omega[n, e*4+hop] = H[n, e]  (hop fastest) =>
// w1_eff[h*64+e] = sum_{q=0..3} w1[h*256 + e*4 + q]
__global__ __launch_bounds__(256) void prep_kernel(const float* __restrict__ w1,
                                                   float* __restrict__ w1_eff) {
    int i = blockIdx.x * 256 + threadIdx.x;          // 0 .. 32767 (exact grid)
    float4 r = *(const float4*)(w1 + (size_t)i * 4);
    w1_eff[i] = r.x + r.y + r.z + r.w;
}

// ---------------- shared per-wave pipeline (block = 64 threads) ----------------
// out_row[o] = (GELU(LN(w1_eff @ H + b1)) @ w2^T + b2)[o], H[e] = dg*proj_b[e] + c·proj_w[e,:]
__device__ __forceinline__ void node_pipeline(
    float dg, float c0, float c1, float c2, float c3,
    const float* __restrict__ proj_w, const float* __restrict__ proj_b,
    const float* __restrict__ w1_eff, const float* __restrict__ b1,
    const float* __restrict__ ln_g, const float* __restrict__ ln_b,
    const float* __restrict__ w2, const float* __restrict__ b2,
    float* __restrict__ out_row, float* lH, float* lg)
{
    int lane = threadIdx.x;                          // 0..63
    // H[lane]
    const float* pw = proj_w + lane * 4;
    lH[lane] = dg * proj_b[lane] + c0 * pw[0] + c1 * pw[1] + c2 * pw[2] + c3 * pw[3];
    __syncthreads();

    // h[hh] for hh = j*64 + lane
    float h[8];
    #pragma unroll
    for (int j = 0; j < 8; ++j) {
        int hh = j * 64 + lane;
        const float4* wr = (const float4*)(w1_eff + hh * EMB);
        float acc = 0.f;
        #pragma unroll
        for (int e4 = 0; e4 < 16; ++e4) {
            float4 w = wr[e4];
            float4 Hv = *(const float4*)(lH + e4 * 4);   // broadcast
            acc += w.x * Hv.x + w.y * Hv.y + w.z * Hv.z + w.w * Hv.w;
        }
        h[j] = acc + b1[hh];
    }

    // LayerNorm stats over all 512 (full-wave butterfly)
    float s = 0.f, ss = 0.f;
    #pragma unroll
    for (int j = 0; j < 8; ++j) { s += h[j]; ss += h[j] * h[j]; }
    #pragma unroll
    for (int d = 1; d < 64; d <<= 1) {
        s  += __shfl_xor(s,  d, 64);
        ss += __shfl_xor(ss, d, 64);
    }
    float mu  = s * (1.0f / 512.0f);
    float var = ss * (1.0f / 512.0f) - mu * mu;
    float rs  = rsqrtf(var + 1e-5f);

    // LN affine + exact GELU -> lg
    #pragma unroll
    for (int j = 0; j < 8; ++j) {
        int hh = j * 64 + lane;
        float x = (h[j] - mu) * rs * ln_g[hh] + ln_b[hh];
        lg[hh] = 0.5f * x * (1.0f + erff(x * 0.70710678118654752f));
    }
    __syncthreads();

    // out[lane] = g · w2[lane,:] + b2[lane]
    const float4* wr2 = (const float4*)(w2 + lane * HID);
    float acc = 0.f;
    #pragma unroll 4
    for (int h4 = 0; h4 < HID / 4; ++h4) {
        float4 w = wr2[h4];
        float4 g = *(const float4*)(lg + h4 * 4);    // broadcast
        acc += w.x * g.x + w.y * g.y + w.z * g.z + w.w * g.w;
    }
    out_row[lane] = acc + b2[lane];
}

// ---------------- Kernel 3: build deg-table (cnt == 0 path) ----------------
__global__ __launch_bounds__(64) void table_kernel(
    const float* __restrict__ proj_w, const float* __restrict__ proj_b,
    const float* __restrict__ w1_eff, const float* __restrict__ b1,
    const float* __restrict__ ln_g, const float* __restrict__ ln_b,
    const float* __restrict__ w2, const float* __restrict__ b2,
    float* __restrict__ table)
{
    __shared__ float lH[EMB];
    __shared__ float lg[HID];
    int d = blockIdx.x;                              // 0 .. DMAX-1
    node_pipeline((float)d, 0.f, 0.f, 0.f, 0.f,
                  proj_w, proj_b, w1_eff, b1, ln_g, ln_b, w2, b2,
                  table + (size_t)d * NOUT, lH, lg);
}

// ---------------- Kernel 4: table scatter (all nodes) ----------------
__global__ __launch_bounds__(256) void copy_kernel(const int* __restrict__ deg,
                                                   const float* __restrict__ table,
                                                   float* __restrict__ out) {
    int t = blockIdx.x * 256 + threadIdx.x;          // 0 .. NB*NN*16-1 (exact grid)
    int gn = t >> 4, q = t & 15;
    int d = deg[gn]; d = d < DMAX - 1 ? d : DMAX - 1;
    ((float4*)out)[(size_t)gn * 16 + q] = ((const float4*)table)[(size_t)d * 16 + q];
}

// ---------------- Kernel 5: exact path for special nodes (overwrites) ----------------
__global__ __launch_bounds__(64) void special_kernel(
    const int* __restrict__ nspec, const int* __restrict__ spec,
    const int* __restrict__ deg, const int* __restrict__ cnt,
    const float* __restrict__ proj_w, const float* __restrict__ proj_b,
    const float* __restrict__ w1_eff, const float* __restrict__ b1,
    const float* __restrict__ ln_g, const float* __restrict__ ln_b,
    const float* __restrict__ w2, const float* __restrict__ b2,
    float* __restrict__ out)
{
    __shared__ float lH[EMB];
    __shared__ float lg[HID];
    int ns = *nspec;
    for (int i = blockIdx.x; i < ns; i += gridDim.x) {
        int gn = spec[i];
        float dg = (float)deg[gn];
        int4 c = *(const int4*)(cnt + gn * 4);
        node_pipeline(dg, (float)c.x, (float)c.y, (float)c.z, (float)c.w,
                      proj_w, proj_b, w1_eff, b1, ln_g, ln_b, w2, b2,
                      out + (size_t)gn * NOUT, lH, lg);
        __syncthreads();
    }
}

// ---------------- launch ----------------
extern "C" void kernel_launch(void* const* d_in, const int* in_sizes, int n_in,
                              void* d_out, int out_size, void* d_ws, size_t ws_size,
                              hipStream_t stream) {
    const int*   ei     = (const int*)d_in[0];
    const int*   pert   = (const int*)d_in[1];
    const float* proj_w = (const float*)d_in[2];
    const float* proj_b = (const float*)d_in[3];
    const float* w1     = (const float*)d_in[4];
    const float* b1     = (const float*)d_in[5];
    const float* ln_g   = (const float*)d_in[6];
    const float* ln_b   = (const float*)d_in[7];
    const float* w2     = (const float*)d_in[8];
    const float* b2     = (const float*)d_in[9];
    float* out = (float*)d_out;

    // workspace layout
    char* ws = (char*)d_ws;
    int*   deg    = (int*)ws;                                  // 32768
    int*   cnt    = (int*)(ws + 32768 * 4);                    // 131072
    int*   nspec  = (int*)(ws + (32768 + 131072) * 4);         // 1
    int*   spec   = nspec + 1;                                  // 32768
    float* w1_eff = (float*)(ws + (32768 + 131072 + 1 + 32768) * 4);   // 32768
    float* table  = w1_eff + 32768;                             // DMAX*64 = 16384

    // zero deg, cnt, nspec
    hipMemsetAsync(ws, 0, (32768 + 131072 + 1) * 4, stream);

    count_kernel   <<<(NB * NE) / 256, 256, 0, stream>>>(ei, pert, deg, cnt);
    classify_kernel<<<(NB * NN) / 256, 256, 0, stream>>>(deg, cnt, nspec, spec);
    prep_kernel    <<<(HID * EMB) / 256, 256, 0, stream>>>(w1, w1_eff);
    table_kernel   <<<DMAX, 64, 0, stream>>>(proj_w, proj_b, w1_eff, b1,
                                             ln_g, ln_b, w2, b2, table);
    copy_kernel    <<<(NB * NN * 16) / 256, 256, 0, stream>>>(deg, table, out);
    special_kernel <<<512, 64, 0, stream>>>(nspec, spec, deg, cnt,
                                            proj_w, proj_b, w1_eff, b1,
                                            ln_g, ln_b, w2, b2, out);
}

// Round 5
// 192.049 us; speedup vs baseline: 1.6710x; 1.0384x over previous
//
#include <hip/hip_runtime.h>
#include <math.h>

#define NN   8192
#define NB   4
#define NE   262144
#define EMB  64
#define HID  512
#define NOUT 64
#define DMAX 256          // table covers deg in [0, DMAX); deg>=DMAX -> special path

// ---------------- Kernel 1: edge counting ----------------
__global__ __launch_bounds__(256) void count_kernel(const int* __restrict__ ei,
                                                    const int* __restrict__ pert,
                                                    int* __restrict__ deg,
                                                    int* __restrict__ cnt) {
    int p0 = pert[0], p1 = pert[1], p2 = pert[2], p3 = pert[3];
    int g = blockIdx.x * 256 + threadIdx.x;          // 0 .. NB*NE-1 (exact grid)
    int b = g >> 18;                                  // NE = 2^18
    int e = g & (NE - 1);
    const int* base = ei + (size_t)b * 2 * NE;
    int src = base[e];
    int dst = base[NE + e];
    int row = b * NN + src;
    atomicAdd(&deg[row], 1);
    if (dst == p0) atomicAdd(&cnt[row * 4 + 0], 1);
    if (dst == p1) atomicAdd(&cnt[row * 4 + 1], 1);
    if (dst == p2) atomicAdd(&cnt[row * 4 + 2], 1);
    if (dst == p3) atomicAdd(&cnt[row * 4 + 3], 1);
}

// ---------------- Kernel 1b: compact list of special nodes ----------------
__global__ __launch_bounds__(256) void classify_kernel(const int* __restrict__ deg,
                                                       const int* __restrict__ cnt,
                                                       int* __restrict__ nspec,
                                                       int* __restrict__ spec) {
    int gn = blockIdx.x * 256 + threadIdx.x;         // 0 .. NB*NN-1 (exact grid)
    int4 c = *(const int4*)(cnt + gn * 4);
    bool sp = ((c.x | c.y | c.z | c.w) != 0) || (deg[gn] >= DMAX);
    if (sp) {
        int i = atomicAdd(nspec, 1);
        spec[i] = gn;
    }
}

// ---------------- Kernel 2: fold hops of w1 + transpose both weights ----------------
// omega[n, e*4+hop] = H[n, e]  =>  w1_eff[hh][e] = sum_{q} w1[hh*256 + e*4 + q]
// Lane-major layouts for coalesced per-wave matvecs:
//   w1t4[(e4*512 + hh)*4 + r] = w1_eff[hh][e4*4 + r]
//   w2t4[(h4*64  +  o)*4 + r] = w2[o*512 + h4*4 + r]
__global__ __launch_bounds__(256) void prep_kernel(const float* __restrict__ w1,
                                                   const float* __restrict__ w2,
                                                   float* __restrict__ w1t4,
                                                   float* __restrict__ w2t4) {
    int i = blockIdx.x * 256 + threadIdx.x;          // 0 .. 65535 (exact grid)
    if (i < 32768) {
        int e4 = i >> 11, hh = (i >> 2) & 511, r = i & 3;
        float4 v = *(const float4*)(w1 + (size_t)hh * 256 + (e4 * 4 + r) * 4);
        w1t4[i] = v.x + v.y + v.z + v.w;
    } else {
        int j = i - 32768;
        int h4 = j >> 8, o = (j >> 2) & 63, r = j & 3;
        w2t4[j] = w2[(size_t)o * 512 + h4 * 4 + r];
    }
}

// ---------------- shared per-wave pipeline (block = 64 threads) ----------------
__device__ __forceinline__ void node_pipeline(
    float dg, float c0, float c1, float c2, float c3,
    const float* __restrict__ proj_w, const float* __restrict__ proj_b,
    const float* __restrict__ w1t4, const float* __restrict__ b1,
    const float* __restrict__ ln_g, const float* __restrict__ ln_b,
    const float* __restrict__ w2t4, const float* __restrict__ b2,
    float* __restrict__ out_row, float* lH, float* lg)
{
    int lane = threadIdx.x;                          // 0..63
    // H[lane]
    const float* pw = proj_w + lane * 4;
    lH[lane] = dg * proj_b[lane] + c0 * pw[0] + c1 * pw[1] + c2 * pw[2] + c3 * pw[3];
    __syncthreads();

    // h[hh], hh = j*64 + lane; w1t4 float4 index (e4*512 + hh): 16B lane stride (coalesced)
    float h[8];
    const float4* W1 = (const float4*)w1t4;
    #pragma unroll
    for (int j = 0; j < 8; ++j) {
        int hh = j * 64 + lane;
        float a0 = 0.f, a1 = 0.f;
        #pragma unroll
        for (int e4 = 0; e4 < 16; e4 += 2) {
            float4 w0 = W1[e4 * 512 + hh];
            float4 H0 = *(const float4*)(lH + e4 * 4);           // broadcast
            float4 w1v = W1[(e4 + 1) * 512 + hh];
            float4 H1 = *(const float4*)(lH + (e4 + 1) * 4);     // broadcast
            a0 += w0.x * H0.x + w0.y * H0.y + w0.z * H0.z + w0.w * H0.w;
            a1 += w1v.x * H1.x + w1v.y * H1.y + w1v.z * H1.z + w1v.w * H1.w;
        }
        h[j] = a0 + a1 + b1[hh];
    }

    // LayerNorm stats over all 512 (full-wave butterfly)
    float s = 0.f, ss = 0.f;
    #pragma unroll
    for (int j = 0; j < 8; ++j) { s += h[j]; ss += h[j] * h[j]; }
    #pragma unroll
    for (int d = 1; d < 64; d <<= 1) {
        s  += __shfl_xor(s,  d, 64);
        ss += __shfl_xor(ss, d, 64);
    }
    float mu  = s * (1.0f / 512.0f);
    float var = ss * (1.0f / 512.0f) - mu * mu;
    float rs  = rsqrtf(var + 1e-5f);

    // LN affine + exact GELU -> lg
    #pragma unroll
    for (int j = 0; j < 8; ++j) {
        int hh = j * 64 + lane;
        float x = (h[j] - mu) * rs * ln_g[hh] + ln_b[hh];
        lg[hh] = 0.5f * x * (1.0f + erff(x * 0.70710678118654752f));
    }
    __syncthreads();

    // out[o], o = lane; w2t4 float4 index (h4*64 + o): 16B lane stride (coalesced)
    const float4* W2 = (const float4*)w2t4;
    float a0 = 0.f, a1 = 0.f;
    #pragma unroll 8
    for (int h4 = 0; h4 < 128; h4 += 2) {
        float4 w0 = W2[h4 * 64 + lane];
        float4 g0 = *(const float4*)(lg + h4 * 4);               // broadcast
        float4 w1v = W2[(h4 + 1) * 64 + lane];
        float4 g1 = *(const float4*)(lg + (h4 + 1) * 4);         // broadcast
        a0 += w0.x * g0.x + w0.y * g0.y + w0.z * g0.z + w0.w * g0.w;
        a1 += w1v.x * g1.x + w1v.y * g1.y + w1v.z * g1.z + w1v.w * g1.w;
    }
    out_row[lane] = a0 + a1 + b2[lane];
}

// ---------------- Kernel 3: build deg-table (cnt == 0 path) ----------------
__global__ __launch_bounds__(64) void table_kernel(
    const float* __restrict__ proj_w, const float* __restrict__ proj_b,
    const float* __restrict__ w1t4, const float* __restrict__ b1,
    const float* __restrict__ ln_g, const float* __restrict__ ln_b,
    const float* __restrict__ w2t4, const float* __restrict__ b2,
    float* __restrict__ table)
{
    __shared__ float lH[EMB];
    __shared__ float lg[HID];
    int d = blockIdx.x;                              // 0 .. DMAX-1
    node_pipeline((float)d, 0.f, 0.f, 0.f, 0.f,
                  proj_w, proj_b, w1t4, b1, ln_g, ln_b, w2t4, b2,
                  table + (size_t)d * NOUT, lH, lg);
}

// ---------------- Kernel 4: table scatter (all nodes) ----------------
__global__ __launch_bounds__(256) void copy_kernel(const int* __restrict__ deg,
                                                   const float* __restrict__ table,
                                                   float* __restrict__ out) {
    int t = blockIdx.x * 256 + threadIdx.x;          // 0 .. NB*NN*16-1 (exact grid)
    int gn = t >> 4, q = t & 15;
    int d = deg[gn]; d = d < DMAX - 1 ? d : DMAX - 1;
    ((float4*)out)[(size_t)gn * 16 + q] = ((const float4*)table)[(size_t)d * 16 + q];
}

// ---------------- Kernel 5: exact path for special nodes (overwrites) ----------------
__global__ __launch_bounds__(64) void special_kernel(
    const int* __restrict__ nspec, const int* __restrict__ spec,
    const int* __restrict__ deg, const int* __restrict__ cnt,
    const float* __restrict__ proj_w, const float* __restrict__ proj_b,
    const float* __restrict__ w1t4, const float* __restrict__ b1,
    const float* __restrict__ ln_g, const float* __restrict__ ln_b,
    const float* __restrict__ w2t4, const float* __restrict__ b2,
    float* __restrict__ out)
{
    __shared__ float lH[EMB];
    __shared__ float lg[HID];
    int ns = *nspec;
    for (int i = blockIdx.x; i < ns; i += gridDim.x) {
        int gn = spec[i];
        float dg = (float)deg[gn];
        int4 c = *(const int4*)(cnt + gn * 4);
        node_pipeline(dg, (float)c.x, (float)c.y, (float)c.z, (float)c.w,
                      proj_w, proj_b, w1t4, b1, ln_g, ln_b, w2t4, b2,
                      out + (size_t)gn * NOUT, lH, lg);
        __syncthreads();
    }
}

// ---------------- launch ----------------
extern "C" void kernel_launch(void* const* d_in, const int* in_sizes, int n_in,
                              void* d_out, int out_size, void* d_ws, size_t ws_size,
                              hipStream_t stream) {
    const int*   ei     = (const int*)d_in[0];
    const int*   pert   = (const int*)d_in[1];
    const float* proj_w = (const float*)d_in[2];
    const float* proj_b = (const float*)d_in[3];
    const float* w1     = (const float*)d_in[4];
    const float* b1     = (const float*)d_in[5];
    const float* ln_g   = (const float*)d_in[6];
    const float* ln_b   = (const float*)d_in[7];
    const float* w2     = (const float*)d_in[8];
    const float* b2     = (const float*)d_in[9];
    float* out = (float*)d_out;

    // workspace layout
    char* ws = (char*)d_ws;
    int*   deg   = (int*)ws;                                   // 32768
    int*   cnt   = (int*)(ws + 32768 * 4);                     // 131072
    int*   nspec = (int*)(ws + (32768 + 131072) * 4);          // 1
    int*   spec  = nspec + 1;                                   // 32768
    float* w1t4  = (float*)(ws + (32768 + 131072 + 1 + 32768) * 4);  // 32768
    float* w2t4  = w1t4 + 32768;                                // 32768
    float* table = w2t4 + 32768;                                // DMAX*64 = 16384

    // zero deg, cnt, nspec
    hipMemsetAsync(ws, 0, (32768 + 131072 + 1) * 4, stream);

    count_kernel   <<<(NB * NE) / 256, 256, 0, stream>>>(ei, pert, deg, cnt);
    classify_kernel<<<(NB * NN) / 256, 256, 0, stream>>>(deg, cnt, nspec, spec);
    prep_kernel    <<<(2 * HID * EMB) / 256, 256, 0, stream>>>(w1, w2, w1t4, w2t4);
    table_kernel   <<<DMAX, 64, 0, stream>>>(proj_w, proj_b, w1t4, b1,
                                             ln_g, ln_b, w2t4, b2, table);
    copy_kernel    <<<(NB * NN * 16) / 256, 256, 0, stream>>>(deg, table, out);
    special_kernel <<<512, 64, 0, stream>>>(nspec, spec, deg, cnt,
                                            proj_w, proj_b, w1t4, b1,
                                            ln_g, ln_b, w2t4, b2, out);
}

// Round 6
// 167.020 us; speedup vs baseline: 1.9214x; 1.1499x over previous
//
#include <hip/hip_runtime.h>
#include <math.h>

#define NN   8192
#define NB   4
#define NE   262144
#define EMB  64
#define HID  512
#define NOUT 64
#define DMAX 256          // table covers deg in [0, DMAX); others go special path
#define SPEC_FLAG (1 << 30)

// ---------------- Kernel 1: edge counting ----------------
__global__ __launch_bounds__(256) void count_kernel(const int* __restrict__ ei,
                                                    const int* __restrict__ pert,
                                                    int* __restrict__ deg,
                                                    int* __restrict__ cnt) {
    int p0 = pert[0], p1 = pert[1], p2 = pert[2], p3 = pert[3];
    int g = blockIdx.x * 256 + threadIdx.x;          // 0 .. NB*NE-1 (exact grid)
    int b = g >> 18;                                  // NE = 2^18
    int e = g & (NE - 1);
    const int* base = ei + (size_t)b * 2 * NE;
    int src = base[e];
    int dst = base[NE + e];
    int row = b * NN + src;
    atomicAdd(&deg[row], 1);
    if (dst == p0) atomicAdd(&cnt[row * 4 + 0], 1);
    if (dst == p1) atomicAdd(&cnt[row * 4 + 1], 1);
    if (dst == p2) atomicAdd(&cnt[row * 4 + 2], 1);
    if (dst == p3) atomicAdd(&cnt[row * 4 + 3], 1);
}

// ---------------- Kernel 2: classify -> flag bit in deg + compact list ----------------
__global__ __launch_bounds__(256) void classify_kernel(const int* __restrict__ cnt,
                                                       int* __restrict__ deg,
                                                       int* __restrict__ nspec,
                                                       int* __restrict__ spec) {
    int gn = blockIdx.x * 256 + threadIdx.x;         // 0 .. NB*NN-1 (exact grid)
    int4 c = *(const int4*)(cnt + gn * 4);
    int d = deg[gn];
    bool sp = ((c.x | c.y | c.z | c.w) != 0) || (d >= DMAX);
    if (sp) {
        int i = atomicAdd(nspec, 1);
        spec[i] = gn;
        deg[gn] = d | SPEC_FLAG;                     // only this thread owns gn
    }
}

// ---------------- Kernel 3: prep ----------------
// blocks 0..1  : u[5][512]: u0 = W1eff@proj_b, u1..4 = W1eff@proj_w[:,j]
//                W1eff[hh][e] = sum_q w1[hh*256 + e*4 + q]  (hop fastest)
// blocks 2..33 : w2t4[(h4*64+o)*4+r] = w2[o*512 + h4*4 + r]  (lane-major for matvec2)
__global__ __launch_bounds__(256) void prep_kernel(const float* __restrict__ w1,
                                                   const float* __restrict__ w2,
                                                   const float* __restrict__ proj_w,
                                                   const float* __restrict__ proj_b,
                                                   float* __restrict__ u,
                                                   float* __restrict__ w2t4) {
    int blk = blockIdx.x, tid = threadIdx.x;
    if (blk < 2) {
        __shared__ float pb[EMB];
        __shared__ float pw[EMB * 4];
        if (tid < EMB) pb[tid] = proj_b[tid];
        pw[tid] = proj_w[tid];                       // 256 threads, 256 elems
        __syncthreads();
        int hh = blk * 256 + tid;                    // 0..511
        const float4* row = (const float4*)(w1 + (size_t)hh * 256);
        float a0 = 0.f, a1 = 0.f, a2 = 0.f, a3 = 0.f, a4 = 0.f;
        #pragma unroll 8
        for (int e = 0; e < 64; ++e) {
            float4 v = row[e];
            float w = v.x + v.y + v.z + v.w;         // fold 4 hop copies
            a0 += w * pb[e];
            a1 += w * pw[e * 4 + 0];
            a2 += w * pw[e * 4 + 1];
            a3 += w * pw[e * 4 + 2];
            a4 += w * pw[e * 4 + 3];
        }
        u[          hh] = a0;
        u[ 512 +    hh] = a1;
        u[1024 +    hh] = a2;
        u[1536 +    hh] = a3;
        u[2048 +    hh] = a4;
    } else {
        int g = (blk - 2) * 256 + tid;               // float4 index, 0..8191
        int o = g >> 7, h4 = g & 127;                // read coalesced (16B lane stride)
        float4 v = *(const float4*)(w2 + (size_t)o * HID + h4 * 4);
        *(float4*)(w2t4 + (size_t)(h4 * 64 + o) * 4) = v;
    }
}

// ---------------- Kernel 4: eval (table entries + special nodes), 1 job / wave ----------------
__global__ __launch_bounds__(512) void eval_kernel(
    const int* __restrict__ nspec, const int* __restrict__ spec,
    const int* __restrict__ deg, const int* __restrict__ cnt,
    const float* __restrict__ u, const float* __restrict__ b1,
    const float* __restrict__ ln_g, const float* __restrict__ ln_b,
    const float* __restrict__ w2t4, const float* __restrict__ b2,
    float* __restrict__ table, float* __restrict__ out)
{
    __shared__ float lg[8][HID];                     // wave-private g buffers, 16 KB
    int tid = threadIdx.x, lane = tid & 63, wid = tid >> 6;

    // per-lane constants (all coalesced loads)
    float U0[8], U1[8], U2[8], U3[8], U4[8], B1r[8], LG[8], LB[8];
    #pragma unroll
    for (int j = 0; j < 8; ++j) {
        int hh = j * 64 + lane;
        U0[j] = u[hh]; U1[j] = u[512 + hh]; U2[j] = u[1024 + hh];
        U3[j] = u[1536 + hh]; U4[j] = u[2048 + hh];
        B1r[j] = b1[hh]; LG[j] = ln_g[hh]; LB[j] = ln_b[hh];
    }
    float b2v = b2[lane];
    int total = DMAX + *nspec;
    float* gbuf = lg[wid];
    const float4* W2 = (const float4*)w2t4;

    for (int i = blockIdx.x * 8 + wid; i < total; i += gridDim.x * 8) {
        float dg, c0, c1, c2, c3;
        float* dst;
        if (i < DMAX) {
            dg = (float)i; c0 = c1 = c2 = c3 = 0.f;
            dst = table + (size_t)i * NOUT;
        } else {
            int gn = spec[i - DMAX];
            dg = (float)(deg[gn] & ~SPEC_FLAG);
            int4 c = *(const int4*)(cnt + gn * 4);
            c0 = (float)c.x; c1 = (float)c.y; c2 = (float)c.z; c3 = (float)c.w;
            dst = out + (size_t)gn * NOUT;
        }
        // h_pre via 5-term linear combination (registers only)
        float h[8], s = 0.f, ss = 0.f;
        #pragma unroll
        for (int j = 0; j < 8; ++j) {
            float v = dg * U0[j] + c0 * U1[j] + c1 * U2[j] + c2 * U3[j] + c3 * U4[j] + B1r[j];
            h[j] = v; s += v; ss += v * v;
        }
        #pragma unroll
        for (int d2 = 1; d2 < 64; d2 <<= 1) {
            s  += __shfl_xor(s,  d2, 64);
            ss += __shfl_xor(ss, d2, 64);
        }
        float mu  = s * (1.0f / 512.0f);
        float var = ss * (1.0f / 512.0f) - mu * mu;
        float rs  = rsqrtf(var + 1e-5f);
        #pragma unroll
        for (int j = 0; j < 8; ++j) {
            float x = (h[j] - mu) * rs * LG[j] + LB[j];
            gbuf[j * 64 + lane] = 0.5f * x * (1.0f + erff(x * 0.70710678118654752f));
        }
        __builtin_amdgcn_wave_barrier();             // order LDS writes before broadcast reads

        // out[lane] = g . w2[lane,:] — coalesced 16B-stride global, broadcast LDS
        float a0 = 0.f, a1 = 0.f;
        #pragma unroll 8
        for (int h4 = 0; h4 < 128; h4 += 2) {
            float4 w0  = W2[h4 * 64 + lane];
            float4 g0  = *(const float4*)(gbuf + h4 * 4);
            float4 w1v = W2[(h4 + 1) * 64 + lane];
            float4 g1  = *(const float4*)(gbuf + (h4 + 1) * 4);
            a0 += w0.x * g0.x + w0.y * g0.y + w0.z * g0.z + w0.w * g0.w;
            a1 += w1v.x * g1.x + w1v.y * g1.y + w1v.z * g1.z + w1v.w * g1.w;
        }
        dst[lane] = a0 + a1 + b2v;
    }
}

// ---------------- Kernel 5: table scatter (skips special nodes) ----------------
__global__ __launch_bounds__(256) void copy_kernel(const int* __restrict__ deg,
                                                   const float* __restrict__ table,
                                                   float* __restrict__ out) {
    int t = blockIdx.x * 256 + threadIdx.x;          // 0 .. NB*NN*16-1 (exact grid)
    int gn = t >> 4, q = t & 15;
    int d = deg[gn];
    if (d & SPEC_FLAG) return;                       // eval wrote this row directly
    d = d < DMAX - 1 ? d : DMAX - 1;
    ((float4*)out)[(size_t)gn * 16 + q] = ((const float4*)table)[(size_t)d * 16 + q];
}

// ---------------- launch ----------------
extern "C" void kernel_launch(void* const* d_in, const int* in_sizes, int n_in,
                              void* d_out, int out_size, void* d_ws, size_t ws_size,
                              hipStream_t stream) {
    const int*   ei     = (const int*)d_in[0];
    const int*   pert   = (const int*)d_in[1];
    const float* proj_w = (const float*)d_in[2];
    const float* proj_b = (const float*)d_in[3];
    const float* w1     = (const float*)d_in[4];
    const float* b1     = (const float*)d_in[5];
    const float* ln_g   = (const float*)d_in[6];
    const float* ln_b   = (const float*)d_in[7];
    const float* w2     = (const float*)d_in[8];
    const float* b2     = (const float*)d_in[9];
    float* out = (float*)d_out;

    // workspace layout
    char* ws = (char*)d_ws;
    int*   deg   = (int*)ws;                                   // 32768
    int*   cnt   = (int*)(ws + 32768 * 4);                     // 131072
    int*   nspec = (int*)(ws + (32768 + 131072) * 4);          // 1
    int*   spec  = nspec + 1;                                   // 32768
    float* u     = (float*)(ws + (32768 + 131072 + 1 + 32768) * 4);  // 2560
    float* w2t4  = u + 2560;                                    // 32768
    float* table = w2t4 + 32768;                                // DMAX*64 = 16384

    // zero deg, cnt, nspec
    hipMemsetAsync(ws, 0, (32768 + 131072 + 1) * 4, stream);

    count_kernel   <<<(NB * NE) / 256, 256, 0, stream>>>(ei, pert, deg, cnt);
    classify_kernel<<<(NB * NN) / 256, 256, 0, stream>>>(cnt, deg, nspec, spec);
    prep_kernel    <<<34, 256, 0, stream>>>(w1, w2, proj_w, proj_b, u, w2t4);
    eval_kernel    <<<96, 512, 0, stream>>>(nspec, spec, deg, cnt, u, b1,
                                            ln_g, ln_b, w2t4, b2, table, out);
    copy_kernel    <<<(NB * NN * 16) / 256, 256, 0, stream>>>(deg, table, out);
}

// Round 7
// 133.997 us; speedup vs baseline: 2.3950x; 1.2464x over previous
//
#include <hip/hip_runtime.h>
#include <math.h>

#define NN   8192
#define NB   4
#define NE   262144
#define EMB  64
#define HID  512
#define NOUT 64
#define DMAX 256          // table covers deg in [0, DMAX); others go special path
#define SPEC_FLAG (1 << 30)
#define SLICES 64         // histogram slices per graph (4096 edges each)

// ---------------- Kernel A: sliced LDS degree histogram + cnt atomics + prep ----------------
// blocks 0..255   : graph b = blk>>6, slice s = blk&63 -> hist_g[blk][8192]
// blocks 256..257 : u[5][512] precompute (w1 hop-fold contracted with proj_b / proj_w cols)
// blocks 258..289 : w2t4 lane-major transpose
__global__ __launch_bounds__(256) void phaseA_kernel(const int* __restrict__ ei,
                                                     const int* __restrict__ pert,
                                                     const float* __restrict__ w1,
                                                     const float* __restrict__ w2,
                                                     const float* __restrict__ proj_w,
                                                     const float* __restrict__ proj_b,
                                                     int* __restrict__ hist_g,
                                                     int* __restrict__ cnt,
                                                     float* __restrict__ u,
                                                     float* __restrict__ w2t4) {
    __shared__ int hist[NN];                         // 32 KB
    int blk = blockIdx.x, tid = threadIdx.x;

    if (blk < NB * SLICES) {
        int b = blk >> 6, s = blk & (SLICES - 1);
        // zero LDS hist (8192 ints, 32 per thread)
        #pragma unroll
        for (int k = 0; k < 8; ++k)
            *(int4*)(hist + (k * 256 + tid) * 4) = make_int4(0, 0, 0, 0);
        __syncthreads();

        int p0 = pert[0], p1 = pert[1], p2 = pert[2], p3 = pert[3];
        const int* src = ei + (size_t)b * 2 * NE + s * 4096;
        const int* dst = src + NE;
        #pragma unroll
        for (int k = 0; k < 4; ++k) {                // 4 int4 = 16 edges / thread
            int4 sv = ((const int4*)src)[k * 256 + tid];
            int4 dv = ((const int4*)dst)[k * 256 + tid];
            atomicAdd(&hist[sv.x], 1);
            atomicAdd(&hist[sv.y], 1);
            atomicAdd(&hist[sv.z], 1);
            atomicAdd(&hist[sv.w], 1);
            int base = b * NN;
            if (dv.x == p0) atomicAdd(&cnt[(base + sv.x) * 4 + 0], 1);
            if (dv.x == p1) atomicAdd(&cnt[(base + sv.x) * 4 + 1], 1);
            if (dv.x == p2) atomicAdd(&cnt[(base + sv.x) * 4 + 2], 1);
            if (dv.x == p3) atomicAdd(&cnt[(base + sv.x) * 4 + 3], 1);
            if (dv.y == p0) atomicAdd(&cnt[(base + sv.y) * 4 + 0], 1);
            if (dv.y == p1) atomicAdd(&cnt[(base + sv.y) * 4 + 1], 1);
            if (dv.y == p2) atomicAdd(&cnt[(base + sv.y) * 4 + 2], 1);
            if (dv.y == p3) atomicAdd(&cnt[(base + sv.y) * 4 + 3], 1);
            if (dv.z == p0) atomicAdd(&cnt[(base + sv.z) * 4 + 0], 1);
            if (dv.z == p1) atomicAdd(&cnt[(base + sv.z) * 4 + 1], 1);
            if (dv.z == p2) atomicAdd(&cnt[(base + sv.z) * 4 + 2], 1);
            if (dv.z == p3) atomicAdd(&cnt[(base + sv.z) * 4 + 3], 1);
            if (dv.w == p0) atomicAdd(&cnt[(base + sv.w) * 4 + 0], 1);
            if (dv.w == p1) atomicAdd(&cnt[(base + sv.w) * 4 + 1], 1);
            if (dv.w == p2) atomicAdd(&cnt[(base + sv.w) * 4 + 2], 1);
            if (dv.w == p3) atomicAdd(&cnt[(base + sv.w) * 4 + 3], 1);
        }
        __syncthreads();
        // flush full histogram (coalesced, no zero-check, no contention)
        int4* hg = (int4*)(hist_g + (size_t)blk * NN);
        #pragma unroll
        for (int k = 0; k < 8; ++k)
            hg[k * 256 + tid] = *(const int4*)(hist + (k * 256 + tid) * 4);
    } else if (blk < NB * SLICES + 2) {
        // u[5][512]: u0 = W1eff@proj_b, u1..4 = W1eff@proj_w[:,j]
        __shared__ float pb[EMB];
        __shared__ float pw[EMB * 4];
        if (tid < EMB) pb[tid] = proj_b[tid];
        pw[tid] = proj_w[tid];
        __syncthreads();
        int hh = (blk - NB * SLICES) * 256 + tid;    // 0..511
        const float4* row = (const float4*)(w1 + (size_t)hh * 256);
        float a0 = 0.f, a1 = 0.f, a2 = 0.f, a3 = 0.f, a4 = 0.f;
        #pragma unroll 8
        for (int e = 0; e < 64; ++e) {
            float4 v = row[e];
            float w = v.x + v.y + v.z + v.w;         // fold 4 hop copies (hop fastest axis)
            a0 += w * pb[e];
            a1 += w * pw[e * 4 + 0];
            a2 += w * pw[e * 4 + 1];
            a3 += w * pw[e * 4 + 2];
            a4 += w * pw[e * 4 + 3];
        }
        u[hh] = a0; u[512 + hh] = a1; u[1024 + hh] = a2; u[1536 + hh] = a3; u[2048 + hh] = a4;
    } else {
        // w2t4[(h4*64+o)*4+r] = w2[o*512 + h4*4 + r]
        int g = (blk - (NB * SLICES + 2)) * 256 + tid;   // float4 index 0..8191
        int o = g >> 7, h4 = g & 127;
        float4 v = *(const float4*)(w2 + (size_t)o * HID + h4 * 4);
        *(float4*)(w2t4 + (size_t)(h4 * 64 + o) * 4) = v;
    }
}

// ---------------- Kernel B: reduce histograms -> deg, classify specials ----------------
__global__ __launch_bounds__(256) void phaseB_kernel(const int* __restrict__ hist_g,
                                                     const int* __restrict__ cnt,
                                                     int* __restrict__ deg,
                                                     int* __restrict__ nspec,
                                                     int* __restrict__ spec) {
    int gn = blockIdx.x * 256 + threadIdx.x;         // 0 .. NB*NN-1 (exact grid)
    int b = gn >> 13, n = gn & (NN - 1);
    const int* hb = hist_g + (size_t)b * SLICES * NN + n;
    int d = 0;
    #pragma unroll 16
    for (int s = 0; s < SLICES; ++s) d += hb[(size_t)s * NN];
    int4 c = *(const int4*)(cnt + gn * 4);
    bool sp = ((c.x | c.y | c.z | c.w) != 0) || (d >= DMAX);
    if (sp) {
        int i = atomicAdd(nspec, 1);
        spec[i] = gn;
        d |= SPEC_FLAG;
    }
    deg[gn] = d;
}

// ---------------- Kernel C: eval (table entries + special nodes), 1 job / wave ----------------
__global__ __launch_bounds__(512) void eval_kernel(
    const int* __restrict__ nspec, const int* __restrict__ spec,
    const int* __restrict__ deg, const int* __restrict__ cnt,
    const float* __restrict__ u, const float* __restrict__ b1,
    const float* __restrict__ ln_g, const float* __restrict__ ln_b,
    const float* __restrict__ w2t4, const float* __restrict__ b2,
    float* __restrict__ table, float* __restrict__ out)
{
    __shared__ float lg[8][HID];                     // wave-private g buffers, 16 KB
    int tid = threadIdx.x, lane = tid & 63, wid = tid >> 6;

    float U0[8], U1[8], U2[8], U3[8], U4[8], B1r[8], LG[8], LB[8];
    #pragma unroll
    for (int j = 0; j < 8; ++j) {
        int hh = j * 64 + lane;
        U0[j] = u[hh]; U1[j] = u[512 + hh]; U2[j] = u[1024 + hh];
        U3[j] = u[1536 + hh]; U4[j] = u[2048 + hh];
        B1r[j] = b1[hh]; LG[j] = ln_g[hh]; LB[j] = ln_b[hh];
    }
    float b2v = b2[lane];
    int total = DMAX + *nspec;
    float* gbuf = lg[wid];
    const float4* W2 = (const float4*)w2t4;

    for (int i = blockIdx.x * 8 + wid; i < total; i += gridDim.x * 8) {
        float dg, c0, c1, c2, c3;
        float* dst;
        if (i < DMAX) {
            dg = (float)i; c0 = c1 = c2 = c3 = 0.f;
            dst = table + (size_t)i * NOUT;
        } else {
            int gn = spec[i - DMAX];
            dg = (float)(deg[gn] & ~SPEC_FLAG);
            int4 c = *(const int4*)(cnt + gn * 4);
            c0 = (float)c.x; c1 = (float)c.y; c2 = (float)c.z; c3 = (float)c.w;
            dst = out + (size_t)gn * NOUT;
        }
        float h[8], s = 0.f, ss = 0.f;
        #pragma unroll
        for (int j = 0; j < 8; ++j) {
            float v = dg * U0[j] + c0 * U1[j] + c1 * U2[j] + c2 * U3[j] + c3 * U4[j] + B1r[j];
            h[j] = v; s += v; ss += v * v;
        }
        #pragma unroll
        for (int d2 = 1; d2 < 64; d2 <<= 1) {
            s  += __shfl_xor(s,  d2, 64);
            ss += __shfl_xor(ss, d2, 64);
        }
        float mu  = s * (1.0f / 512.0f);
        float var = ss * (1.0f / 512.0f) - mu * mu;
        float rs  = rsqrtf(var + 1e-5f);
        #pragma unroll
        for (int j = 0; j < 8; ++j) {
            float x = (h[j] - mu) * rs * LG[j] + LB[j];
            gbuf[j * 64 + lane] = 0.5f * x * (1.0f + erff(x * 0.70710678118654752f));
        }
        __builtin_amdgcn_wave_barrier();

        float a0 = 0.f, a1 = 0.f;
        #pragma unroll 8
        for (int h4 = 0; h4 < 128; h4 += 2) {
            float4 w0  = W2[h4 * 64 + lane];
            float4 g0  = *(const float4*)(gbuf + h4 * 4);
            float4 w1v = W2[(h4 + 1) * 64 + lane];
            float4 g1  = *(const float4*)(gbuf + (h4 + 1) * 4);
            a0 += w0.x * g0.x + w0.y * g0.y + w0.z * g0.z + w0.w * g0.w;
            a1 += w1v.x * g1.x + w1v.y * g1.y + w1v.z * g1.z + w1v.w * g1.w;
        }
        dst[lane] = a0 + a1 + b2v;
    }
}

// ---------------- Kernel D: table scatter (skips special nodes) ----------------
__global__ __launch_bounds__(256) void copy_kernel(const int* __restrict__ deg,
                                                   const float* __restrict__ table,
                                                   float* __restrict__ out) {
    int t = blockIdx.x * 256 + threadIdx.x;          // 0 .. NB*NN*16-1 (exact grid)
    int gn = t >> 4, q = t & 15;
    int d = deg[gn];
    if (d & SPEC_FLAG) return;                       // eval wrote this row directly
    d = d < DMAX - 1 ? d : DMAX - 1;
    ((float4*)out)[(size_t)gn * 16 + q] = ((const float4*)table)[(size_t)d * 16 + q];
}

// ---------------- launch ----------------
extern "C" void kernel_launch(void* const* d_in, const int* in_sizes, int n_in,
                              void* d_out, int out_size, void* d_ws, size_t ws_size,
                              hipStream_t stream) {
    const int*   ei     = (const int*)d_in[0];
    const int*   pert   = (const int*)d_in[1];
    const float* proj_w = (const float*)d_in[2];
    const float* proj_b = (const float*)d_in[3];
    const float* w1     = (const float*)d_in[4];
    const float* b1     = (const float*)d_in[5];
    const float* ln_g   = (const float*)d_in[6];
    const float* ln_b   = (const float*)d_in[7];
    const float* w2     = (const float*)d_in[8];
    const float* b2     = (const float*)d_in[9];
    float* out = (float*)d_out;

    // workspace layout
    char* ws = (char*)d_ws;
    int*   deg    = (int*)ws;                                   // 32768
    int*   cnt    = deg + 32768;                                // 131072  (memset w/ nspec)
    int*   nspec  = cnt + 131072;                               // 1
    int*   spec   = nspec + 1;                                  // 32768
    float* u      = (float*)(spec + 32768);                     // 2560
    float* w2t4   = u + 2560;                                   // 32768
    float* table  = w2t4 + 32768;                               // 16384
    int*   hist_g = (int*)(table + 16384);                      // 256*8192 = 2M ints (8 MB)

    // zero cnt + nspec (contiguous); deg/hist fully overwritten by kernels
    hipMemsetAsync(cnt, 0, (131072 + 1) * 4, stream);

    phaseA_kernel<<<NB * SLICES + 34, 256, 0, stream>>>(ei, pert, w1, w2, proj_w, proj_b,
                                                        hist_g, cnt, u, w2t4);
    phaseB_kernel<<<(NB * NN) / 256, 256, 0, stream>>>(hist_g, cnt, deg, nspec, spec);
    eval_kernel  <<<96, 512, 0, stream>>>(nspec, spec, deg, cnt, u, b1,
                                          ln_g, ln_b, w2t4, b2, table, out);
    copy_kernel  <<<(NB * NN * 16) / 256, 256, 0, stream>>>(deg, table, out);
}

// Round 8
// 128.238 us; speedup vs baseline: 2.5025x; 1.0449x over previous
//
#include <hip/hip_runtime.h>
#include <math.h>

#define NN   8192
#define NB   4
#define NE   262144
#define EMB  64
#define HID  512
#define NOUT 64
#define DMAX 256          // table covers deg in [0, DMAX); others go special path
#define SPEC_FLAG (1 << 30)
#define SLICES 32         // 8192 edges per slice; per-slice deg counts fit u16
#define HBLK (NB * SLICES)            // 128 histogram blocks
#define HWORDS (NN / 2)               // 4096 packed u32 per slice histogram

// ---------------- shared per-wave evaluator ----------------
// dst[lane] = (GELU(LN(dg*u0 + c·u1..4 + b1)) @ w2^T + b2)[lane]
__device__ __forceinline__ void eval_one(
    float dg, float c0, float c1, float c2, float c3,
    const float* __restrict__ u, const float* __restrict__ b1,
    const float* __restrict__ ln_g, const float* __restrict__ ln_b,
    const float* __restrict__ w2t4, const float* __restrict__ b2,
    float* __restrict__ gbuf, float* __restrict__ dst, int lane)
{
    float h[8], s = 0.f, ss = 0.f;
    #pragma unroll
    for (int j = 0; j < 8; ++j) {
        int hh = j * 64 + lane;
        float v = dg * u[hh] + c0 * u[512 + hh] + c1 * u[1024 + hh]
                + c2 * u[1536 + hh] + c3 * u[2048 + hh] + b1[hh];
        h[j] = v; s += v; ss += v * v;
    }
    #pragma unroll
    for (int d2 = 1; d2 < 64; d2 <<= 1) {
        s  += __shfl_xor(s,  d2, 64);
        ss += __shfl_xor(ss, d2, 64);
    }
    float mu  = s * (1.0f / 512.0f);
    float var = ss * (1.0f / 512.0f) - mu * mu;
    float rs  = rsqrtf(var + 1e-5f);
    #pragma unroll
    for (int j = 0; j < 8; ++j) {
        int hh = j * 64 + lane;
        float x = (h[j] - mu) * rs * ln_g[hh] + ln_b[hh];
        gbuf[hh] = 0.5f * x * (1.0f + erff(x * 0.70710678118654752f));
    }
    __builtin_amdgcn_wave_barrier();                 // LDS writes before broadcast reads

    const float4* W2 = (const float4*)w2t4;
    float a0 = 0.f, a1 = 0.f;
    #pragma unroll 8
    for (int h4 = 0; h4 < 128; h4 += 2) {
        float4 w0  = W2[h4 * 64 + lane];
        float4 g0  = *(const float4*)(gbuf + h4 * 4);
        float4 w1v = W2[(h4 + 1) * 64 + lane];
        float4 g1  = *(const float4*)(gbuf + (h4 + 1) * 4);
        a0 += w0.x * g0.x + w0.y * g0.y + w0.z * g0.z + w0.w * g0.w;
        a1 += w1v.x * g1.x + w1v.y * g1.y + w1v.z * g1.z + w1v.w * g1.w;
    }
    dst[lane] = a0 + a1 + b2[lane];
    __builtin_amdgcn_wave_barrier();                 // reads done before next job's writes
}

// ---------------- Kernel A: u16-packed LDS degree hist + cnt atomics + prep ----------------
// blocks 0..127   : graph b = blk>>5, slice s = blk&31 -> hist_g[blk][4096] (u16 pairs)
// blocks 128..129 : u[5][512] precompute
// blocks 130..161 : w2t4 lane-major transpose
__global__ __launch_bounds__(256) void phaseA_kernel(const int* __restrict__ ei,
                                                     const int* __restrict__ pert,
                                                     const float* __restrict__ w1,
                                                     const float* __restrict__ w2,
                                                     const float* __restrict__ proj_w,
                                                     const float* __restrict__ proj_b,
                                                     unsigned int* __restrict__ hist_g,
                                                     int* __restrict__ cnt,
                                                     float* __restrict__ u,
                                                     float* __restrict__ w2t4) {
    __shared__ unsigned int hist[HWORDS];            // 16 KB packed u16 counters
    __shared__ float pb[EMB];
    __shared__ float pw[EMB * 4];
    int blk = blockIdx.x, tid = threadIdx.x;

    if (blk < HBLK) {
        int b = blk >> 5, s = blk & (SLICES - 1);
        #pragma unroll
        for (int k = 0; k < 4; ++k)
            *(uint4*)(hist + (k * 256 + tid) * 4) = make_uint4(0, 0, 0, 0);
        __syncthreads();

        int p0 = pert[0], p1 = pert[1], p2 = pert[2], p3 = pert[3];
        const int* src = ei + (size_t)b * 2 * NE + s * (NE / SLICES);
        const int* dst = src + NE;
        int base = b * NN;
        #pragma unroll
        for (int k = 0; k < 8; ++k) {                // 8 int4 = 32 edges / thread
            int4 sv = ((const int4*)src)[k * 256 + tid];
            int4 dv = ((const int4*)dst)[k * 256 + tid];
            atomicAdd(&hist[sv.x >> 1], 1u << ((sv.x & 1) << 4));
            atomicAdd(&hist[sv.y >> 1], 1u << ((sv.y & 1) << 4));
            atomicAdd(&hist[sv.z >> 1], 1u << ((sv.z & 1) << 4));
            atomicAdd(&hist[sv.w >> 1], 1u << ((sv.w & 1) << 4));
            if (dv.x == p0) atomicAdd(&cnt[(base + sv.x) * 4 + 0], 1);
            if (dv.x == p1) atomicAdd(&cnt[(base + sv.x) * 4 + 1], 1);
            if (dv.x == p2) atomicAdd(&cnt[(base + sv.x) * 4 + 2], 1);
            if (dv.x == p3) atomicAdd(&cnt[(base + sv.x) * 4 + 3], 1);
            if (dv.y == p0) atomicAdd(&cnt[(base + sv.y) * 4 + 0], 1);
            if (dv.y == p1) atomicAdd(&cnt[(base + sv.y) * 4 + 1], 1);
            if (dv.y == p2) atomicAdd(&cnt[(base + sv.y) * 4 + 2], 1);
            if (dv.y == p3) atomicAdd(&cnt[(base + sv.y) * 4 + 3], 1);
            if (dv.z == p0) atomicAdd(&cnt[(base + sv.z) * 4 + 0], 1);
            if (dv.z == p1) atomicAdd(&cnt[(base + sv.z) * 4 + 1], 1);
            if (dv.z == p2) atomicAdd(&cnt[(base + sv.z) * 4 + 2], 1);
            if (dv.z == p3) atomicAdd(&cnt[(base + sv.z) * 4 + 3], 1);
            if (dv.w == p0) atomicAdd(&cnt[(base + sv.w) * 4 + 0], 1);
            if (dv.w == p1) atomicAdd(&cnt[(base + sv.w) * 4 + 1], 1);
            if (dv.w == p2) atomicAdd(&cnt[(base + sv.w) * 4 + 2], 1);
            if (dv.w == p3) atomicAdd(&cnt[(base + sv.w) * 4 + 3], 1);
        }
        __syncthreads();
        uint4* hg = (uint4*)(hist_g + (size_t)blk * HWORDS);
        #pragma unroll
        for (int k = 0; k < 4; ++k)
            hg[k * 256 + tid] = *(const uint4*)(hist + (k * 256 + tid) * 4);
    } else if (blk < HBLK + 2) {
        if (tid < EMB) pb[tid] = proj_b[tid];
        pw[tid] = proj_w[tid];
        __syncthreads();
        int hh = (blk - HBLK) * 256 + tid;           // 0..511
        const float4* row = (const float4*)(w1 + (size_t)hh * 256);
        float a0 = 0.f, a1 = 0.f, a2 = 0.f, a3 = 0.f, a4 = 0.f;
        #pragma unroll 8
        for (int e = 0; e < 64; ++e) {
            float4 v = row[e];
            float w = v.x + v.y + v.z + v.w;         // fold 4 hop copies (hop fastest)
            a0 += w * pb[e];
            a1 += w * pw[e * 4 + 0];
            a2 += w * pw[e * 4 + 1];
            a3 += w * pw[e * 4 + 2];
            a4 += w * pw[e * 4 + 3];
        }
        u[hh] = a0; u[512 + hh] = a1; u[1024 + hh] = a2; u[1536 + hh] = a3; u[2048 + hh] = a4;
    } else {
        int g = (blk - (HBLK + 2)) * 256 + tid;      // float4 index 0..8191
        int o = g >> 7, h4 = g & 127;
        float4 v = *(const float4*)(w2 + (size_t)o * HID + h4 * 4);
        *(float4*)(w2t4 + (size_t)(h4 * 64 + o) * 4) = v;
    }
}

// ---------------- Kernel B: reduce hist -> deg + classify, AND build table ----------------
// blocks 0..127  : per-node degree reduce + special classification
// blocks 128..191: table entries (1 per wave, 4 waves/block = 256 entries)
__global__ __launch_bounds__(256) void phaseB_kernel(
    const unsigned int* __restrict__ hist_g, const int* __restrict__ cnt,
    int* __restrict__ deg, int* __restrict__ nspec, int* __restrict__ spec,
    const float* __restrict__ u, const float* __restrict__ b1,
    const float* __restrict__ ln_g, const float* __restrict__ ln_b,
    const float* __restrict__ w2t4, const float* __restrict__ b2,
    float* __restrict__ table)
{
    __shared__ float lg[4][HID];                     // 8 KB (table blocks only)
    int blk = blockIdx.x, tid = threadIdx.x;
    if (blk < 128) {
        int gn = blk * 256 + tid;                    // 0 .. NB*NN-1
        int b = gn >> 13, n = gn & (NN - 1);
        const unsigned int* hb = hist_g + (size_t)b * SLICES * HWORDS + (n >> 1);
        int sh = (n & 1) << 4;
        int d = 0;
        #pragma unroll 8
        for (int s = 0; s < SLICES; ++s) d += (hb[s * HWORDS] >> sh) & 0xFFFFu;
        int4 c = *(const int4*)(cnt + gn * 4);
        bool sp = ((c.x | c.y | c.z | c.w) != 0) || (d >= DMAX);
        if (sp) {
            int i = atomicAdd(nspec, 1);
            spec[i] = gn;
            d |= SPEC_FLAG;
        }
        deg[gn] = d;
    } else {
        int lane = tid & 63, wid = tid >> 6;
        int i = (blk - 128) * 4 + wid;               // 0..255 exactly
        eval_one((float)i, 0.f, 0.f, 0.f, 0.f, u, b1, ln_g, ln_b, w2t4, b2,
                 lg[wid], table + (size_t)i * NOUT, lane);
    }
}

// ---------------- Kernel C: table scatter + special-node eval ----------------
// blocks 0..2047   : copy table rows to all non-special nodes
// blocks 2048..2175: exact eval for special nodes (grid-stride, 1 job/wave)
__global__ __launch_bounds__(256) void phaseC_kernel(
    const int* __restrict__ nspec, const int* __restrict__ spec,
    const int* __restrict__ deg, const int* __restrict__ cnt,
    const float* __restrict__ u, const float* __restrict__ b1,
    const float* __restrict__ ln_g, const float* __restrict__ ln_b,
    const float* __restrict__ w2t4, const float* __restrict__ b2,
    const float* __restrict__ table, float* __restrict__ out)
{
    __shared__ float lg[4][HID];                     // 8 KB (special blocks only)
    int blk = blockIdx.x, tid = threadIdx.x;
    if (blk < 2048) {
        int t = blk * 256 + tid;                     // 0 .. NB*NN*16-1
        int gn = t >> 4, q = t & 15;
        int d = deg[gn];
        if (d & SPEC_FLAG) return;                   // eval writes this row directly
        d = d < DMAX - 1 ? d : DMAX - 1;
        ((float4*)out)[(size_t)gn * 16 + q] = ((const float4*)table)[(size_t)d * 16 + q];
    } else {
        int lane = tid & 63, wid = tid >> 6;
        int ns = *nspec;
        for (int i = (blk - 2048) * 4 + wid; i < ns; i += 128 * 4) {
            int gn = spec[i];
            float dg = (float)(deg[gn] & ~SPEC_FLAG);
            int4 c = *(const int4*)(cnt + gn * 4);
            eval_one(dg, (float)c.x, (float)c.y, (float)c.z, (float)c.w,
                     u, b1, ln_g, ln_b, w2t4, b2,
                     lg[wid], out + (size_t)gn * NOUT, lane);
        }
    }
}

// ---------------- launch ----------------
extern "C" void kernel_launch(void* const* d_in, const int* in_sizes, int n_in,
                              void* d_out, int out_size, void* d_ws, size_t ws_size,
                              hipStream_t stream) {
    const int*   ei     = (const int*)d_in[0];
    const int*   pert   = (const int*)d_in[1];
    const float* proj_w = (const float*)d_in[2];
    const float* proj_b = (const float*)d_in[3];
    const float* w1     = (const float*)d_in[4];
    const float* b1     = (const float*)d_in[5];
    const float* ln_g   = (const float*)d_in[6];
    const float* ln_b   = (const float*)d_in[7];
    const float* w2     = (const float*)d_in[8];
    const float* b2     = (const float*)d_in[9];
    float* out = (float*)d_out;

    // workspace layout
    char* ws = (char*)d_ws;
    int*          deg    = (int*)ws;                            // 32768
    int*          cnt    = deg + 32768;                         // 131072 (zeroed w/ nspec)
    int*          nspec  = cnt + 131072;                        // 1
    int*          spec   = nspec + 1;                           // 32768
    float*        u      = (float*)(spec + 32768);              // 2560
    float*        w2t4   = u + 2560;                            // 32768
    float*        table  = w2t4 + 32768;                        // 16384
    unsigned int* hist_g = (unsigned int*)(table + 16384);      // 128*4096 u32 = 2 MB

    hipMemsetAsync(cnt, 0, (131072 + 1) * 4, stream);           // cnt + nspec

    phaseA_kernel<<<HBLK + 34, 256, 0, stream>>>(ei, pert, w1, w2, proj_w, proj_b,
                                                 hist_g, cnt, u, w2t4);
    phaseB_kernel<<<192, 256, 0, stream>>>(hist_g, cnt, deg, nspec, spec,
                                           u, b1, ln_g, ln_b, w2t4, b2, table);
    phaseC_kernel<<<2176, 256, 0, stream>>>(nspec, spec, deg, cnt,
                                            u, b1, ln_g, ln_b, w2t4, b2, table, out);
}

// Round 9
// 105.917 us; speedup vs baseline: 3.0299x; 1.2107x over previous
//
#include <hip/hip_runtime.h>
#include <math.h>

#define NN   8192
#define NB   4
#define NE   262144
#define EMB  64
#define HID  512
#define NOUT 64
#define DMAX 256          // table covers deg in [0, DMAX); others go special path
#define SPEC_FLAG (1 << 30)
#define SLICES 32         // 8192 edges per slice; per-slice deg counts fit u16
#define HBLK (NB * SLICES)            // 128 histogram blocks
#define HWORDS (NN / 2)               // 4096 packed u32 per slice histogram

// ---------------- block-level evaluator (256 threads = 4 waves, one job) ----------------
// dst[0..63] = (GELU(LN(dg*u0 + c·u1..4 + b1)) @ w2^T + b2)
__device__ __forceinline__ void eval_block(
    float dg, float c0, float c1, float c2, float c3,
    const float* __restrict__ u, const float* __restrict__ b1,
    const float* __restrict__ ln_g, const float* __restrict__ ln_b,
    const float* __restrict__ w2t4, const float* __restrict__ b2,
    float* __restrict__ dst,
    float* __restrict__ g,       // [HID] LDS
    float* __restrict__ pacc,    // [4*64] LDS
    float* __restrict__ red)     // [8] LDS
{
    int tid = threadIdx.x, lane = tid & 63, wid = tid >> 6;

    // h for hh = tid and tid+256 (2 per thread)
    int h1i = tid + 256;
    float h0 = dg * u[tid] + c0 * u[512 + tid] + c1 * u[1024 + tid]
             + c2 * u[1536 + tid] + c3 * u[2048 + tid] + b1[tid];
    float h1 = dg * u[h1i] + c0 * u[512 + h1i] + c1 * u[1024 + h1i]
             + c2 * u[1536 + h1i] + c3 * u[2048 + h1i] + b1[h1i];

    float s = h0 + h1, ss = h0 * h0 + h1 * h1;
    #pragma unroll
    for (int d2 = 1; d2 < 64; d2 <<= 1) {
        s  += __shfl_xor(s,  d2, 64);
        ss += __shfl_xor(ss, d2, 64);
    }
    if (lane == 0) { red[wid] = s; red[4 + wid] = ss; }
    __syncthreads();
    float S  = red[0] + red[1] + red[2] + red[3];
    float SS = red[4] + red[5] + red[6] + red[7];
    float mu  = S * (1.0f / 512.0f);
    float var = SS * (1.0f / 512.0f) - mu * mu;
    float rs  = rsqrtf(var + 1e-5f);

    float x0 = (h0 - mu) * rs * ln_g[tid] + ln_b[tid];
    g[tid]  = 0.5f * x0 * (1.0f + erff(x0 * 0.70710678118654752f));
    float x1 = (h1 - mu) * rs * ln_g[h1i] + ln_b[h1i];
    g[h1i]  = 0.5f * x1 * (1.0f + erff(x1 * 0.70710678118654752f));
    __syncthreads();

    // matvec2: wave wid covers h4-chunks [wid*32, wid*32+32)
    const float4* W2 = (const float4*)w2t4;
    int h4b = wid * 32;
    float a0 = 0.f, a1 = 0.f;
    #pragma unroll 8
    for (int k = 0; k < 32; k += 2) {
        float4 w0  = W2[(h4b + k) * 64 + lane];
        float4 g0  = *(const float4*)(g + (h4b + k) * 4);        // broadcast
        float4 w1v = W2[(h4b + k + 1) * 64 + lane];
        float4 g1  = *(const float4*)(g + (h4b + k + 1) * 4);    // broadcast
        a0 += w0.x * g0.x + w0.y * g0.y + w0.z * g0.z + w0.w * g0.w;
        a1 += w1v.x * g1.x + w1v.y * g1.y + w1v.z * g1.z + w1v.w * g1.w;
    }
    pacc[wid * 64 + lane] = a0 + a1;
    __syncthreads();
    if (tid < 64)
        dst[tid] = pacc[tid] + pacc[64 + tid] + pacc[128 + tid] + pacc[192 + tid] + b2[tid];
    __syncthreads();                                             // LDS safe for next job
}

// ---------------- Kernel A: u16-packed LDS degree hist + cnt atomics + prep ----------------
// blocks 0..127   : graph b = blk>>5, slice s = blk&31 -> hist_g[blk][4096] (u16 pairs)
// blocks 128..129 : u[5][512] precompute
// blocks 130..161 : w2t4 lane-major transpose
__global__ __launch_bounds__(256) void phaseA_kernel(const int* __restrict__ ei,
                                                     const int* __restrict__ pert,
                                                     const float* __restrict__ w1,
                                                     const float* __restrict__ w2,
                                                     const float* __restrict__ proj_w,
                                                     const float* __restrict__ proj_b,
                                                     unsigned int* __restrict__ hist_g,
                                                     int* __restrict__ cnt,
                                                     float* __restrict__ u,
                                                     float* __restrict__ w2t4) {
    __shared__ unsigned int hist[HWORDS];            // 16 KB packed u16 counters
    __shared__ float pb[EMB];
    __shared__ float pw[EMB * 4];
    int blk = blockIdx.x, tid = threadIdx.x;

    if (blk < HBLK) {
        int b = blk >> 5, s = blk & (SLICES - 1);
        #pragma unroll
        for (int k = 0; k < 4; ++k)
            *(uint4*)(hist + (k * 256 + tid) * 4) = make_uint4(0, 0, 0, 0);
        __syncthreads();

        int p0 = pert[0], p1 = pert[1], p2 = pert[2], p3 = pert[3];
        const int* src = ei + (size_t)b * 2 * NE + s * (NE / SLICES);
        const int* dst = src + NE;
        int base = b * NN;
        #pragma unroll
        for (int k = 0; k < 8; ++k) {                // 8 int4 = 32 edges / thread
            int4 sv = ((const int4*)src)[k * 256 + tid];
            int4 dv = ((const int4*)dst)[k * 256 + tid];
            atomicAdd(&hist[sv.x >> 1], 1u << ((sv.x & 1) << 4));
            atomicAdd(&hist[sv.y >> 1], 1u << ((sv.y & 1) << 4));
            atomicAdd(&hist[sv.z >> 1], 1u << ((sv.z & 1) << 4));
            atomicAdd(&hist[sv.w >> 1], 1u << ((sv.w & 1) << 4));
            if (dv.x == p0) atomicAdd(&cnt[(base + sv.x) * 4 + 0], 1);
            if (dv.x == p1) atomicAdd(&cnt[(base + sv.x) * 4 + 1], 1);
            if (dv.x == p2) atomicAdd(&cnt[(base + sv.x) * 4 + 2], 1);
            if (dv.x == p3) atomicAdd(&cnt[(base + sv.x) * 4 + 3], 1);
            if (dv.y == p0) atomicAdd(&cnt[(base + sv.y) * 4 + 0], 1);
            if (dv.y == p1) atomicAdd(&cnt[(base + sv.y) * 4 + 1], 1);
            if (dv.y == p2) atomicAdd(&cnt[(base + sv.y) * 4 + 2], 1);
            if (dv.y == p3) atomicAdd(&cnt[(base + sv.y) * 4 + 3], 1);
            if (dv.z == p0) atomicAdd(&cnt[(base + sv.z) * 4 + 0], 1);
            if (dv.z == p1) atomicAdd(&cnt[(base + sv.z) * 4 + 1], 1);
            if (dv.z == p2) atomicAdd(&cnt[(base + sv.z) * 4 + 2], 1);
            if (dv.z == p3) atomicAdd(&cnt[(base + sv.z) * 4 + 3], 1);
            if (dv.w == p0) atomicAdd(&cnt[(base + sv.w) * 4 + 0], 1);
            if (dv.w == p1) atomicAdd(&cnt[(base + sv.w) * 4 + 1], 1);
            if (dv.w == p2) atomicAdd(&cnt[(base + sv.w) * 4 + 2], 1);
            if (dv.w == p3) atomicAdd(&cnt[(base + sv.w) * 4 + 3], 1);
        }
        __syncthreads();
        uint4* hg = (uint4*)(hist_g + (size_t)blk * HWORDS);
        #pragma unroll
        for (int k = 0; k < 4; ++k)
            hg[k * 256 + tid] = *(const uint4*)(hist + (k * 256 + tid) * 4);
    } else if (blk < HBLK + 2) {
        if (tid < EMB) pb[tid] = proj_b[tid];
        pw[tid] = proj_w[tid];
        __syncthreads();
        int hh = (blk - HBLK) * 256 + tid;           // 0..511
        const float4* row = (const float4*)(w1 + (size_t)hh * 256);
        float a0 = 0.f, a1 = 0.f, a2 = 0.f, a3 = 0.f, a4 = 0.f;
        #pragma unroll 8
        for (int e = 0; e < 64; ++e) {
            float4 v = row[e];
            float w = v.x + v.y + v.z + v.w;         // fold 4 hop copies (hop fastest)
            a0 += w * pb[e];
            a1 += w * pw[e * 4 + 0];
            a2 += w * pw[e * 4 + 1];
            a3 += w * pw[e * 4 + 2];
            a4 += w * pw[e * 4 + 3];
        }
        u[hh] = a0; u[512 + hh] = a1; u[1024 + hh] = a2; u[1536 + hh] = a3; u[2048 + hh] = a4;
    } else {
        int g = (blk - (HBLK + 2)) * 256 + tid;      // float4 index 0..8191
        int o = g >> 7, h4 = g & 127;
        float4 v = *(const float4*)(w2 + (size_t)o * HID + h4 * 4);
        *(float4*)(w2t4 + (size_t)(h4 * 64 + o) * 4) = v;
    }
}

// ---------------- Kernel B: reduce hist -> deg + classify, AND table (1 job/block) ------
// blocks 0..127  : per-node degree reduce + special classification
// blocks 128..383: table entry i = blk-128 (block-level eval)
__global__ __launch_bounds__(256) void phaseB_kernel(
    const unsigned int* __restrict__ hist_g, const int* __restrict__ cnt,
    int* __restrict__ deg, int* __restrict__ nspec, int* __restrict__ spec,
    const float* __restrict__ u, const float* __restrict__ b1,
    const float* __restrict__ ln_g, const float* __restrict__ ln_b,
    const float* __restrict__ w2t4, const float* __restrict__ b2,
    float* __restrict__ table)
{
    __shared__ float g[HID];
    __shared__ float pacc[4 * 64];
    __shared__ float red[8];
    int blk = blockIdx.x, tid = threadIdx.x;
    if (blk < 128) {
        int gn = blk * 256 + tid;                    // 0 .. NB*NN-1
        int b = gn >> 13, n = gn & (NN - 1);
        const unsigned int* hb = hist_g + (size_t)b * SLICES * HWORDS + (n >> 1);
        int sh = (n & 1) << 4;
        int d = 0;
        #pragma unroll 8
        for (int s = 0; s < SLICES; ++s) d += (hb[s * HWORDS] >> sh) & 0xFFFFu;
        int4 c = *(const int4*)(cnt + gn * 4);
        bool sp = ((c.x | c.y | c.z | c.w) != 0) || (d >= DMAX);
        if (sp) {
            int i = atomicAdd(nspec, 1);
            spec[i] = gn;
            d |= SPEC_FLAG;
        }
        deg[gn] = d;
    } else {
        int i = blk - 128;                           // 0..255
        eval_block((float)i, 0.f, 0.f, 0.f, 0.f, u, b1, ln_g, ln_b, w2t4, b2,
                   table + (size_t)i * NOUT, g, pacc, red);
    }
}

// ---------------- Kernel C: table scatter + special-node eval (1 job/block) ----------------
// blocks 0..2047   : copy table rows to all non-special nodes
// blocks 2048..2559: exact eval for special nodes (grid-stride)
__global__ __launch_bounds__(256) void phaseC_kernel(
    const int* __restrict__ nspec, const int* __restrict__ spec,
    const int* __restrict__ deg, const int* __restrict__ cnt,
    const float* __restrict__ u, const float* __restrict__ b1,
    const float* __restrict__ ln_g, const float* __restrict__ ln_b,
    const float* __restrict__ w2t4, const float* __restrict__ b2,
    const float* __restrict__ table, float* __restrict__ out)
{
    __shared__ float g[HID];
    __shared__ float pacc[4 * 64];
    __shared__ float red[8];
    int blk = blockIdx.x, tid = threadIdx.x;
    if (blk < 2048) {
        int t = blk * 256 + tid;                     // 0 .. NB*NN*16-1
        int gn = t >> 4, q = t & 15;
        int d = deg[gn];
        if (d & SPEC_FLAG) return;                   // eval writes this row directly
        d = d < DMAX - 1 ? d : DMAX - 1;
        ((float4*)out)[(size_t)gn * 16 + q] = ((const float4*)table)[(size_t)d * 16 + q];
    } else {
        int ns = *nspec;
        for (int i = blk - 2048; i < ns; i += 512) {
            int gn = spec[i];
            float dg = (float)(deg[gn] & ~SPEC_FLAG);
            int4 c = *(const int4*)(cnt + gn * 4);
            eval_block(dg, (float)c.x, (float)c.y, (float)c.z, (float)c.w,
                       u, b1, ln_g, ln_b, w2t4, b2,
                       out + (size_t)gn * NOUT, g, pacc, red);
        }
    }
}

// ---------------- launch ----------------
extern "C" void kernel_launch(void* const* d_in, const int* in_sizes, int n_in,
                              void* d_out, int out_size, void* d_ws, size_t ws_size,
                              hipStream_t stream) {
    const int*   ei     = (const int*)d_in[0];
    const int*   pert   = (const int*)d_in[1];
    const float* proj_w = (const float*)d_in[2];
    const float* proj_b = (const float*)d_in[3];
    const float* w1     = (const float*)d_in[4];
    const float* b1     = (const float*)d_in[5];
    const float* ln_g   = (const float*)d_in[6];
    const float* ln_b   = (const float*)d_in[7];
    const float* w2     = (const float*)d_in[8];
    const float* b2     = (const float*)d_in[9];
    float* out = (float*)d_out;

    // workspace layout
    char* ws = (char*)d_ws;
    int*          deg    = (int*)ws;                            // 32768
    int*          cnt    = deg + 32768;                         // 131072 (zeroed w/ nspec)
    int*          nspec  = cnt + 131072;                        // 1
    int*          spec   = nspec + 1;                           // 32768
    float*        u      = (float*)(spec + 32768);              // 2560
    float*        w2t4   = u + 2560;                            // 32768
    float*        table  = w2t4 + 32768;                        // 16384
    unsigned int* hist_g = (unsigned int*)(table + 16384);      // 128*4096 u32 = 2 MB

    hipMemsetAsync(cnt, 0, (131072 + 1) * 4, stream);           // cnt + nspec

    phaseA_kernel<<<HBLK + 34, 256, 0, stream>>>(ei, pert, w1, w2, proj_w, proj_b,
                                                 hist_g, cnt, u, w2t4);
    phaseB_kernel<<<384, 256, 0, stream>>>(hist_g, cnt, deg, nspec, spec,
                                           u, b1, ln_g, ln_b, w2t4, b2, table);
    phaseC_kernel<<<2560, 256, 0, stream>>>(nspec, spec, deg, cnt,
                                            u, b1, ln_g, ln_b, w2t4, b2, table, out);
}